// Round 5
// baseline (299.341 us; speedup 1.0000x reference)
//
#include <hip/hip_runtime.h>
#include <hip/hip_bf16.h>

#define E_DIM 768
#define H_DIM 64
#define B_SZ 8
#define T_SZ 4096
#define BT (B_SZ * T_SZ)   // 32768

typedef __attribute__((ext_vector_type(8))) short short8;   // 8 bf16 (MFMA A/B frag)
typedef __attribute__((ext_vector_type(4))) float floatx4;  // MFMA C/D frag

// raw barrier: LDS visibility only — does NOT drain vmcnt (prefetch stays in flight)
#define RAWBAR() __asm__ volatile("s_waitcnt lgkmcnt(0)\n\ts_barrier" ::: "memory")

static __device__ __forceinline__ unsigned short bf1(float a) {
    __hip_bfloat16 h = __float2bfloat16(a);
    unsigned short u; __builtin_memcpy(&u, &h, 2); return u;
}
static __device__ __forceinline__ unsigned int pk2(float a, float b) {
    __hip_bfloat162 h = __float22bfloat162_rn(float2{a, b});
    unsigned int u; __builtin_memcpy(&u, &h, 4); return u;
}

// ---------------- W transpose + bf16: Wt[n][k], n = nt*64+nn ----------------
// Wq additionally scaled by log2(e) so attention softmax can use exp2 directly.
__global__ __launch_bounds__(256) void prep_w(
    const float* __restrict__ Wq, const float* __restrict__ Wk,
    const float* __restrict__ Wv, unsigned short* __restrict__ Wt)
{
    __shared__ float Ls[64][65];
    const int nt = blockIdx.x;           // 0..2
    const int kc = blockIdx.y;           // 0..11 (64-k chunk)
    const float* __restrict__ W = (nt == 0) ? Wq : (nt == 1) ? Wk : Wv;
    const float scl = (nt == 0) ? 1.44269504088896f : 1.0f;
    const int t = threadIdx.x;
    const int k0 = kc * 64;

#pragma unroll
    for (int it = 0; it < 16; ++it) {
        const int kk = (t >> 6) + it * 4;
        Ls[kk][t & 63] = W[(size_t)(k0 + kk) * H_DIM + (t & 63)];
    }
    __syncthreads();

#pragma unroll
    for (int it = 0; it < 4; ++it) {
        const int nl = (t >> 4) + it * 16;
        const int kl = (t & 15) * 4;
        unsigned int u[2];
        u[0] = pk2(Ls[kl + 0][nl] * scl, Ls[kl + 1][nl] * scl);
        u[1] = pk2(Ls[kl + 2][nl] * scl, Ls[kl + 3][nl] * scl);
        *(uint2*)(Wt + (size_t)(nt * 64 + nl) * E_DIM + k0 + kl) = *(uint2*)u;
    }
}

// ---------------- projection: W-in-registers, 32-row X tiles double-buffered ----------------
// grid 256, 768 threads = 12 waves; wave w owns n-tile w (Q:0-3, K:4-7, V:8-11).
// Block covers 128 M-rows = 4 m-tiles of 32 (2 MFMA sub-tiles each).
__global__ __launch_bounds__(768, 3) void proj_mfma(
    const float* __restrict__ X, const unsigned short* __restrict__ Wt,
    unsigned short* __restrict__ Qb, unsigned short* __restrict__ Kb,
    unsigned short* __restrict__ Vtb)
{
    __shared__ unsigned short Xs[2][32][776];   // 32-row X tile bf16, pad 776

    const int tid  = threadIdx.x;
    const int wave = tid >> 6, lane = tid & 63;
    const int row  = lane & 15, quad = lane >> 4;
    const int m0   = blockIdx.x * 128;

    // W prologue: 24 B-frags resident in registers (96 VGPRs)
    short8 bfr[24];
    {
        const unsigned short* wp = Wt + (size_t)(wave * 16 + row) * E_DIM + quad * 8;
#pragma unroll
        for (int ks = 0; ks < 24; ++ks) bfr[ks] = *(const short8*)(wp + ks * 32);
    }

    // X staging: thread -> (row = tid&31, 32-float chunk sc = tid>>5 in 0..23)
    const int srow = tid & 31;
    const int sc   = tid >> 5;
    const float* __restrict__ xbase = X + (size_t)(m0 + srow) * E_DIM + sc * 32;

    float4 fx[8];
#define LDX(mt)                                                               \
    {                                                                         \
        const float* p = xbase + (size_t)(mt) * 32 * E_DIM;                   \
        _Pragma("unroll")                                                     \
        for (int i = 0; i < 8; ++i) fx[i] = *(const float4*)(p + i * 4);      \
    }
#define STX(buf)                                                              \
    {                                                                         \
        unsigned int tmp[16];                                                 \
        _Pragma("unroll")                                                     \
        for (int i = 0; i < 8; ++i) {                                         \
            tmp[2 * i]     = pk2(fx[i].x, fx[i].y);                           \
            tmp[2 * i + 1] = pk2(fx[i].z, fx[i].w);                           \
        }                                                                     \
        _Pragma("unroll")                                                     \
        for (int i = 0; i < 4; ++i)                                           \
            *(int4*)&Xs[buf][srow][sc * 32 + i * 8] = *(int4*)&tmp[4 * i];    \
    }

    LDX(0); STX(0);
    RAWBAR();

    const int g  = wave >> 2;            // 0=Q, 1=K, 2=V
    const int h  = (wave & 3) * 16 + row;
    unsigned short* __restrict__ OQK = (g == 0) ? Qb : Kb;
    const int bb = m0 >> 12;             // batch (block never crosses batch: 128 | 4096)

    int cur = 0;
    for (int mt = 0; mt < 4; ++mt) {
        if (mt < 3) LDX(mt + 1);

        floatx4 acc[2] = {(floatx4)0.0f, (floatx4)0.0f};
#pragma unroll
        for (int ks = 0; ks < 24; ++ks) {
#pragma unroll
            for (int ms = 0; ms < 2; ++ms) {
                const short8 af = *(const short8*)&Xs[cur][ms * 16 + row][ks * 32 + quad * 8];
                acc[ms] = __builtin_amdgcn_mfma_f32_16x16x32_bf16(af, bfr[ks], acc[ms], 0, 0, 0);
            }
        }

        // store C: D col = lane&15 (n), row = quad*4+r (m)
#pragma unroll
        for (int ms = 0; ms < 2; ++ms) {
            const int mr = m0 + mt * 32 + ms * 16 + quad * 4;
            if (g < 2) {
#pragma unroll
                for (int r = 0; r < 4; ++r)
                    OQK[(size_t)(mr + r) * H_DIM + h] = bf1(acc[ms][r]);
            } else {
                const int t0 = mr & 4095;
                unsigned int u[2];
                u[0] = pk2(acc[ms][0], acc[ms][1]); u[1] = pk2(acc[ms][2], acc[ms][3]);
                *(uint2*)(Vtb + ((size_t)bb * H_DIM + h) * T_SZ + t0) = *(uint2*)u;
            }
        }

        if (mt < 3) STX(cur ^ 1);
        RAWBAR();
        cur ^= 1;
    }
#undef LDX
#undef STX
}

// ---------------- flash attention: K direct-from-global, V triple-buffered LDS ----------------
typedef unsigned short KVrow[72];

__global__ __launch_bounds__(256, 4) void attn_mfma(
    const unsigned short* __restrict__ Qb,
    const unsigned short* __restrict__ Kb,
    const unsigned short* __restrict__ Vtb,
    float* __restrict__ Out)
{
    __shared__ unsigned short Vs[3][64][72];   // V^T [h][key_local], triple-buffered
    __shared__ unsigned short Ps[4][16][76];   // per-wave P [q][key], pad 76

    const int lb   = blockIdx.x;
    const int b    = lb & 7;
    const int qt   = 63 - (lb >> 3);           // heavy q-tiles first
    const int tid  = threadIdx.x;
    const int wave = tid >> 6, lane = tid & 63;
    const int row  = lane & 15, quad = lane >> 4;

    const size_t base = (size_t)b * T_SZ * H_DIM;
    const int q0 = qt * 64 + wave * 16;

    // V^T staging: 32B per lane per tile
    const int vh = tid >> 2, vseg = (tid & 3) * 16;
    const unsigned short* __restrict__ Vsrc = Vtb + ((size_t)b * H_DIM + vh) * T_SZ + vseg;
    // K fragments read directly from global (L2-resident; per-batch K = 512 KB)
    const unsigned short* __restrict__ Kfrag = Kb + base + (size_t)row * H_DIM + quad * 8;

    short8 qf0, qf1;
    {
        const unsigned short* qp = Qb + base + (size_t)(q0 + row) * H_DIM + quad * 8;
        qf0 = *(const short8*)(qp);
        qf1 = *(const short8*)(qp + 32);
    }

    floatx4 o[4];
#pragma unroll
    for (int i = 0; i < 4; ++i) o[i] = (floatx4)0.0f;
    float lp[4] = {0.0f, 0.0f, 0.0f, 0.0f};

    KVrow* vp0 = Vs[0]; KVrow* vp1 = Vs[1]; KVrow* vp2 = Vs[2];
    int4 vA0, vA1, vB0, vB1;

#define LDV(V0, V1, t)                                                   \
    {                                                                    \
        const unsigned short* vp = Vsrc + (t) * 64;                      \
        V0 = *(const int4*)vp; V1 = *(const int4*)(vp + 8);              \
    }
#define STV(V0, V1, VD)                                                  \
    { *(int4*)&VD[vh][vseg] = V0; *(int4*)&VD[vh][vseg + 8] = V1; }
#define ROTATE()                                                         \
    { KVrow* tv = vp0; vp0 = vp1; vp1 = vp2; vp2 = tv; }

    auto compute = [&](int t, KVrow* vc) {
        // S = Q K^T : K B-frags straight from global
        const unsigned short* kp = Kfrag + (size_t)t * 64 * H_DIM;
        floatx4 s[4];
#pragma unroll
        for (int nt = 0; nt < 4; ++nt) {
            const short8 kf0 = *(const short8*)(kp + nt * 16 * H_DIM);
            const short8 kf1 = *(const short8*)(kp + nt * 16 * H_DIM + 32);
            floatx4 a = (floatx4)0.0f;
            a = __builtin_amdgcn_mfma_f32_16x16x32_bf16(qf0, kf0, a, 0, 0, 0);
            a = __builtin_amdgcn_mfma_f32_16x16x32_bf16(qf1, kf1, a, 0, 0, 0);
            s[nt] = a;
        }
        if (t == qt) {                         // causal mask on diagonal tile
#pragma unroll
            for (int nt = 0; nt < 4; ++nt) {
                const int key_loc = nt * 16 + row;
#pragma unroll
                for (int r = 0; r < 4; ++r)
                    if (key_loc > wave * 16 + quad * 4 + r) s[nt][r] = -1e30f;
            }
        }
        // softmax (Q pre-scaled by log2e): p = exp2(min(s,110)); l deferred
#pragma unroll
        for (int r = 0; r < 4; ++r) {
#pragma unroll
            for (int nt = 0; nt < 4; ++nt) {
                const float pv = exp2f(fminf(s[nt][r], 110.0f));
                lp[r] += pv;
                Ps[wave][quad * 4 + r][nt * 16 + row] = bf1(pv);
            }
        }
        __builtin_amdgcn_wave_barrier();       // per-wave LDS RAW ordering fence
#pragma unroll
        for (int kst = 0; kst < 2; ++kst) {
            const short8 pa = *(const short8*)(&Ps[wave][row][kst * 32 + quad * 8]);
#pragma unroll
            for (int nt = 0; nt < 4; ++nt) {
                const short8 vb = *(const short8*)(&vc[nt * 16 + row][kst * 32 + quad * 8]);
                o[nt] = __builtin_amdgcn_mfma_f32_16x16x32_bf16(pa, vb, o[nt], 0, 0, 0);
            }
        }
    };

    // prologue: tile0 via set A -> buf0; tile1 -> set B
    LDV(vA0, vA1, 0);
    STV(vA0, vA1, vp0);
    if (qt >= 1) LDV(vB0, vB1, 1);
    RAWBAR();

    int kt = 0;
    while (true) {
        if (kt + 2 <= qt) LDV(vA0, vA1, kt + 2);
        if (kt + 1 <= qt) STV(vB0, vB1, vp1);
        compute(kt, vp0);
        RAWBAR();
        ROTATE();
        ++kt;
        if (kt > qt) break;

        if (kt + 2 <= qt) LDV(vB0, vB1, kt + 2);
        if (kt + 1 <= qt) STV(vA0, vA1, vp1);
        compute(kt, vp0);
        RAWBAR();
        ROTATE();
        ++kt;
        if (kt > qt) break;
    }

    // epilogue: one 16-lane l-reduction per row, normalize, store
#pragma unroll
    for (int r = 0; r < 4; ++r) {
        float l = lp[r];
#pragma unroll
        for (int off = 1; off < 16; off <<= 1)
            l += __shfl_xor(l, off, 16);
        const float inv = 1.0f / l;
        float* op = Out + base + (size_t)(q0 + quad * 4 + r) * H_DIM + row;
#pragma unroll
        for (int nt = 0; nt < 4; ++nt)
            op[nt * 16] = o[nt][r] * inv;
    }
#undef LDV
#undef STV
#undef ROTATE
}

extern "C" void kernel_launch(void* const* d_in, const int* in_sizes, int n_in,
                              void* d_out, int out_size, void* d_ws, size_t ws_size,
                              hipStream_t stream) {
    const float* X  = (const float*)d_in[0];
    const float* Wq = (const float*)d_in[1];
    const float* Wk = (const float*)d_in[2];
    const float* Wv = (const float*)d_in[3];

    unsigned short* Wt  = (unsigned short*)d_ws;            // 192*768 bf16
    unsigned short* Qb  = Wt + (size_t)192 * E_DIM;
    unsigned short* Kb  = Qb + (size_t)BT * H_DIM;
    unsigned short* Vtb = Kb + (size_t)BT * H_DIM;          // V transposed [b][h][t]

    prep_w<<<dim3(3, 12), 256, 0, stream>>>(Wq, Wk, Wv, Wt);
    proj_mfma<<<256, 768, 0, stream>>>(X, Wt, Qb, Kb, Vtb);
    attn_mfma<<<512, 256, 0, stream>>>(Qb, Kb, Vtb, (float*)d_out);
}

// Round 6
// 291.121 us; speedup vs baseline: 1.0282x; 1.0282x over previous
//
#include <hip/hip_runtime.h>
#include <hip/hip_bf16.h>

#define E_DIM 768
#define H_DIM 64
#define B_SZ 8
#define T_SZ 4096
#define BT (B_SZ * T_SZ)   // 32768

typedef __attribute__((ext_vector_type(8))) short short8;   // 8 bf16 (MFMA A/B frag)
typedef __attribute__((ext_vector_type(4))) float floatx4;  // MFMA C/D frag

// raw barrier: LDS visibility only — does NOT drain vmcnt (prefetch stays in flight)
#define RAWBAR() __asm__ volatile("s_waitcnt lgkmcnt(0)\n\ts_barrier" ::: "memory")

static __device__ __forceinline__ unsigned short bf1(float a) {
    __hip_bfloat16 h = __float2bfloat16(a);
    unsigned short u; __builtin_memcpy(&u, &h, 2); return u;
}
static __device__ __forceinline__ unsigned int pk2(float a, float b) {
    __hip_bfloat162 h = __float22bfloat162_rn(float2{a, b});
    unsigned int u; __builtin_memcpy(&u, &h, 4); return u;
}

// ---------------- W transpose + bf16: Wt[n][k], n = nt*64+nn ----------------
// Wq additionally scaled by log2(e) so attention softmax can use exp2 directly.
__global__ __launch_bounds__(256) void prep_w(
    const float* __restrict__ Wq, const float* __restrict__ Wk,
    const float* __restrict__ Wv, unsigned short* __restrict__ Wt)
{
    __shared__ float Ls[64][65];
    const int nt = blockIdx.x;           // 0..2
    const int kc = blockIdx.y;           // 0..11 (64-k chunk)
    const float* __restrict__ W = (nt == 0) ? Wq : (nt == 1) ? Wk : Wv;
    const float scl = (nt == 0) ? 1.44269504088896f : 1.0f;
    const int t = threadIdx.x;
    const int k0 = kc * 64;

#pragma unroll
    for (int it = 0; it < 16; ++it) {
        const int kk = (t >> 6) + it * 4;
        Ls[kk][t & 63] = W[(size_t)(k0 + kk) * H_DIM + (t & 63)];
    }
    __syncthreads();

#pragma unroll
    for (int it = 0; it < 4; ++it) {
        const int nl = (t >> 4) + it * 16;
        const int kl = (t & 15) * 4;
        unsigned int u[2];
        u[0] = pk2(Ls[kl + 0][nl] * scl, Ls[kl + 1][nl] * scl);
        u[1] = pk2(Ls[kl + 2][nl] * scl, Ls[kl + 3][nl] * scl);
        *(uint2*)(Wt + (size_t)(nt * 64 + nl) * E_DIM + k0 + kl) = *(uint2*)u;
    }
}

// ---------------- projection: W-in-registers, X double-buffered in LDS (R4 version) ----------------
// grid 256, 768 threads = 12 waves; wave w owns n-tile w (Q:0-3, K:4-7, V:8-11).
__global__ __launch_bounds__(768) void proj_mfma(
    const float* __restrict__ X, const unsigned short* __restrict__ Wt,
    unsigned short* __restrict__ Qb, unsigned short* __restrict__ Kb,
    unsigned short* __restrict__ Vtb)
{
    __shared__ unsigned short Xs[2][16][776];   // 16-row X tile bf16, pad 776

    const int tid  = threadIdx.x;
    const int wave = tid >> 6, lane = tid & 63;
    const int row  = lane & 15, quad = lane >> 4;
    const int m0   = blockIdx.x * 128;

    // W prologue: 24 B-frags resident in registers (96 VGPRs)
    short8 bfr[24];
    {
        const unsigned short* wp = Wt + (size_t)(wave * 16 + row) * E_DIM + quad * 8;
#pragma unroll
        for (int ks = 0; ks < 24; ++ks) bfr[ks] = *(const short8*)(wp + ks * 32);
    }

    const int srow = tid & 15;
    const int sc   = tid >> 4;
    const float* __restrict__ xbase = X + (size_t)(m0 + srow) * E_DIM + sc * 16;

    float4 fx[4];
#define LDX(mt)                                                               \
    {                                                                         \
        const float* p = xbase + (size_t)(mt) * 16 * E_DIM;                   \
        fx[0] = *(const float4*)(p);     fx[1] = *(const float4*)(p + 4);     \
        fx[2] = *(const float4*)(p + 8); fx[3] = *(const float4*)(p + 12);    \
    }
#define STX(buf)                                                              \
    {                                                                         \
        unsigned int tmp[8];                                                  \
        tmp[0] = pk2(fx[0].x, fx[0].y); tmp[1] = pk2(fx[0].z, fx[0].w);       \
        tmp[2] = pk2(fx[1].x, fx[1].y); tmp[3] = pk2(fx[1].z, fx[1].w);       \
        tmp[4] = pk2(fx[2].x, fx[2].y); tmp[5] = pk2(fx[2].z, fx[2].w);       \
        tmp[6] = pk2(fx[3].x, fx[3].y); tmp[7] = pk2(fx[3].z, fx[3].w);       \
        *(int4*)&Xs[buf][srow][sc * 16]     = *(int4*)&tmp[0];                \
        *(int4*)&Xs[buf][srow][sc * 16 + 8] = *(int4*)&tmp[4];                \
    }

    LDX(0); STX(0);
    RAWBAR();

    const int g  = wave >> 2;            // 0=Q, 1=K, 2=V
    const int h  = (wave & 3) * 16 + row;
    unsigned short* __restrict__ OQK = (g == 0) ? Qb : Kb;
    const int bb = m0 >> 12;

    int cur = 0;
    for (int mt = 0; mt < 8; ++mt) {
        if (mt < 7) LDX(mt + 1);

        floatx4 acc = (floatx4)0.0f;
#pragma unroll
        for (int ks = 0; ks < 24; ++ks) {
            const short8 af = *(const short8*)&Xs[cur][row][ks * 32 + quad * 8];
            acc = __builtin_amdgcn_mfma_f32_16x16x32_bf16(af, bfr[ks], acc, 0, 0, 0);
        }

        const int mr = m0 + mt * 16 + quad * 4;
        if (g < 2) {
#pragma unroll
            for (int r = 0; r < 4; ++r)
                OQK[(size_t)(mr + r) * H_DIM + h] = bf1(acc[r]);
        } else {
            const int t0 = mr & 4095;
            unsigned int u[2];
            u[0] = pk2(acc[0], acc[1]); u[1] = pk2(acc[2], acc[3]);
            *(uint2*)(Vtb + ((size_t)bb * H_DIM + h) * T_SZ + t0) = *(uint2*)u;
        }

        if (mt < 7) STX(cur ^ 1);
        RAWBAR();
        cur ^= 1;
    }
#undef LDX
#undef STX
}

// ---------------- flash attention: split-K over 4 waves, 16-row q-tiles ----------------
// block = (batch, 16-row q-tile); wave w handles k-tiles w, w+4, w+8, ...
// No-max softmax => partial (O,l) are additive; one LDS combine per block.
__global__ __launch_bounds__(256, 3) void attn_mfma(
    const unsigned short* __restrict__ Qb,
    const unsigned short* __restrict__ Kb,
    const unsigned short* __restrict__ Vtb,
    float* __restrict__ Out)
{
    __shared__ unsigned short Ps[4][16][76];   // per-wave P [q][key], pad 76
    __shared__ float Oc[4][16][64];            // per-wave O partial
    __shared__ float lc[4][16];                // per-wave l partial

    const int lb   = blockIdx.x;
    const int b    = lb & 7;                   // batch -> XCD (L2 locality)
    const int qq   = 255 - (lb >> 3);          // q-tile, heavy first (LPT)
    const int tid  = threadIdx.x;
    const int wave = tid >> 6, lane = tid & 63;
    const int col  = lane & 15, quad = lane >> 4;

    const size_t base = (size_t)b * T_SZ * H_DIM;
    const int q0  = qq * 16;
    const int nkt = (qq >> 2) + 1;             // k-tiles for this q-tile
    const int ktd = nkt - 1;                   // diagonal tile

    // Q fragments (same q-tile for all 4 waves)
    short8 qf0, qf1;
    {
        const unsigned short* qp = Qb + base + (size_t)(q0 + col) * H_DIM + quad * 8;
        qf0 = *(const short8*)(qp);
        qf1 = *(const short8*)(qp + 32);
    }

    floatx4 o[4];
#pragma unroll
    for (int i = 0; i < 4; ++i) o[i] = (floatx4)0.0f;
    float lp[4] = {0.0f, 0.0f, 0.0f, 0.0f};

    // frag base pointers
    // K frag (tile kt, ntile nt, kstep ks): Kfb + (kt*64 + nt*16)*64 + ks*32
    const unsigned short* __restrict__ Kfb = Kb + base + (size_t)col * H_DIM + quad * 8;
    // V^T frag: Vfb + nt*16*T_SZ + kt*64 + ks*32
    const unsigned short* __restrict__ Vfb = Vtb + ((size_t)b * H_DIM + col) * T_SZ + quad * 8;

    short8 kA[8], kB[8];

#define LOADK(dst, kt)                                                        \
    {                                                                         \
        const unsigned short* kp = Kfb + (size_t)(kt) * 64 * H_DIM;           \
        _Pragma("unroll")                                                     \
        for (int nt = 0; nt < 4; ++nt) {                                      \
            dst[nt * 2 + 0] = *(const short8*)(kp + nt * 16 * H_DIM);         \
            dst[nt * 2 + 1] = *(const short8*)(kp + nt * 16 * H_DIM + 32);    \
        }                                                                     \
    }

    auto compute = [&](int kt, const short8 (&kf)[8]) {
        // V frags for this tile: issued first, consumed after exp chain
        short8 vf[8];
#pragma unroll
        for (int nt = 0; nt < 4; ++nt) {
            const unsigned short* vp = Vfb + (size_t)nt * 16 * T_SZ + kt * 64;
            vf[nt * 2 + 0] = *(const short8*)(vp);
            vf[nt * 2 + 1] = *(const short8*)(vp + 32);
        }

        floatx4 s[4];
#pragma unroll
        for (int nt = 0; nt < 4; ++nt) {
            floatx4 a = (floatx4)0.0f;
            a = __builtin_amdgcn_mfma_f32_16x16x32_bf16(qf0, kf[nt * 2 + 0], a, 0, 0, 0);
            a = __builtin_amdgcn_mfma_f32_16x16x32_bf16(qf1, kf[nt * 2 + 1], a, 0, 0, 0);
            s[nt] = a;
        }

        if (kt == ktd) {                       // causal mask on diagonal tile
#pragma unroll
            for (int nt = 0; nt < 4; ++nt) {
                const int keyg = kt * 64 + nt * 16 + col;
#pragma unroll
                for (int r = 0; r < 4; ++r)
                    if (keyg > q0 + quad * 4 + r) s[nt][r] = -1e30f;
            }
        }

        // no-max softmax (Q pre-scaled by log2e): p = exp2(min(s,110))
#pragma unroll
        for (int r = 0; r < 4; ++r) {
#pragma unroll
            for (int nt = 0; nt < 4; ++nt) {
                const float pv = exp2f(fminf(s[nt][r], 110.0f));
                lp[r] += pv;
                Ps[wave][quad * 4 + r][nt * 16 + col] = bf1(pv);
            }
        }
        __builtin_amdgcn_wave_barrier();       // per-wave LDS RAW ordering fence

        // O += P V
#pragma unroll
        for (int ks = 0; ks < 2; ++ks) {
            const short8 pa = *(const short8*)(&Ps[wave][col][ks * 32 + quad * 8]);
#pragma unroll
            for (int nt = 0; nt < 4; ++nt)
                o[nt] = __builtin_amdgcn_mfma_f32_16x16x32_bf16(pa, vf[nt * 2 + ks], o[nt], 0, 0, 0);
        }
    };

    // main loop: wave-private k-tiles, K double-buffered one tile ahead
    int kt = wave;
    if (kt < nkt) LOADK(kA, kt);
    while (kt < nkt) {
        if (kt + 4 < nkt) LOADK(kB, kt + 4);
        compute(kt, kA);
        kt += 4;
        if (kt >= nkt) break;
        if (kt + 4 < nkt) LOADK(kA, kt + 4);
        compute(kt, kB);
        kt += 4;
    }

    // write partials
#pragma unroll
    for (int r = 0; r < 4; ++r) {
        float l = lp[r];
#pragma unroll
        for (int off = 1; off < 16; off <<= 1)
            l += __shfl_xor(l, off, 16);
        if (col == 0) lc[wave][quad * 4 + r] = l;
#pragma unroll
        for (int nt = 0; nt < 4; ++nt)
            Oc[wave][quad * 4 + r][nt * 16 + col] = o[nt][r];
    }
    __syncthreads();

    // combine: 256 threads over 16 rows x 16 dim-chunks of 4
    {
        const int orow = tid >> 4, d0 = (tid & 15) * 4;
        float4 acc = {0.0f, 0.0f, 0.0f, 0.0f};
#pragma unroll
        for (int w = 0; w < 4; ++w) {
            const float4 t4 = *(const float4*)&Oc[w][orow][d0];
            acc.x += t4.x; acc.y += t4.y; acc.z += t4.z; acc.w += t4.w;
        }
        const float l = lc[0][orow] + lc[1][orow] + lc[2][orow] + lc[3][orow];
        const float inv = 1.0f / l;
        acc.x *= inv; acc.y *= inv; acc.z *= inv; acc.w *= inv;
        *(float4*)(Out + base + (size_t)(q0 + orow) * H_DIM + d0) = acc;
    }
#undef LOADK
}

extern "C" void kernel_launch(void* const* d_in, const int* in_sizes, int n_in,
                              void* d_out, int out_size, void* d_ws, size_t ws_size,
                              hipStream_t stream) {
    const float* X  = (const float*)d_in[0];
    const float* Wq = (const float*)d_in[1];
    const float* Wk = (const float*)d_in[2];
    const float* Wv = (const float*)d_in[3];

    unsigned short* Wt  = (unsigned short*)d_ws;            // 192*768 bf16
    unsigned short* Qb  = Wt + (size_t)192 * E_DIM;
    unsigned short* Kb  = Qb + (size_t)BT * H_DIM;
    unsigned short* Vtb = Kb + (size_t)BT * H_DIM;          // V transposed [b][h][t]

    prep_w<<<dim3(3, 12), 256, 0, stream>>>(Wq, Wk, Wv, Wt);
    proj_mfma<<<256, 768, 0, stream>>>(X, Wt, Qb, Kb, Vtb);
    attn_mfma<<<2048, 256, 0, stream>>>(Qb, Kb, Vtb, (float*)d_out);
}

// Round 7
// 230.787 us; speedup vs baseline: 1.2970x; 1.2614x over previous
//
#include <hip/hip_runtime.h>
#include <hip/hip_bf16.h>

#define E_DIM 768
#define H_DIM 64
#define B_SZ 8
#define T_SZ 4096
#define BT (B_SZ * T_SZ)   // 32768

typedef __attribute__((ext_vector_type(8))) short short8;   // 8 bf16 (MFMA A/B frag)
typedef __attribute__((ext_vector_type(4))) float floatx4;  // MFMA C/D frag

// raw barrier: LDS visibility only — does NOT drain vmcnt (prefetch stays in flight)
#define RAWBAR() __asm__ volatile("s_waitcnt lgkmcnt(0)\n\ts_barrier" ::: "memory")

static __device__ __forceinline__ unsigned short bf1(float a) {
    __hip_bfloat16 h = __float2bfloat16(a);
    unsigned short u; __builtin_memcpy(&u, &h, 2); return u;
}
static __device__ __forceinline__ unsigned int pk2(float a, float b) {
    __hip_bfloat162 h = __float22bfloat162_rn(float2{a, b});
    unsigned int u; __builtin_memcpy(&u, &h, 4); return u;
}

// ---------------- W transpose + bf16: Wt[n][k], n = nt*64+nn ----------------
// Wq additionally scaled by log2(e) so attention softmax can use exp2 directly.
__global__ __launch_bounds__(256) void prep_w(
    const float* __restrict__ Wq, const float* __restrict__ Wk,
    const float* __restrict__ Wv, unsigned short* __restrict__ Wt)
{
    __shared__ float Ls[64][65];
    const int nt = blockIdx.x;           // 0..2
    const int kc = blockIdx.y;           // 0..11 (64-k chunk)
    const float* __restrict__ W = (nt == 0) ? Wq : (nt == 1) ? Wk : Wv;
    const float scl = (nt == 0) ? 1.44269504088896f : 1.0f;
    const int t = threadIdx.x;
    const int k0 = kc * 64;

#pragma unroll
    for (int it = 0; it < 16; ++it) {
        const int kk = (t >> 6) + it * 4;
        Ls[kk][t & 63] = W[(size_t)(k0 + kk) * H_DIM + (t & 63)];
    }
    __syncthreads();

#pragma unroll
    for (int it = 0; it < 4; ++it) {
        const int nl = (t >> 4) + it * 16;
        const int kl = (t & 15) * 4;
        unsigned int u[2];
        u[0] = pk2(Ls[kl + 0][nl] * scl, Ls[kl + 1][nl] * scl);
        u[1] = pk2(Ls[kl + 2][nl] * scl, Ls[kl + 3][nl] * scl);
        *(uint2*)(Wt + (size_t)(nt * 64 + nl) * E_DIM + k0 + kl) = *(uint2*)u;
    }
}

// ---------------- projection: W-in-registers, X double-buffered in LDS ----------------
// grid 256, 768 threads = 12 waves; wave w owns n-tile w (Q:0-3, K:4-7, V:8-11).
__global__ __launch_bounds__(768) void proj_mfma(
    const float* __restrict__ X, const unsigned short* __restrict__ Wt,
    unsigned short* __restrict__ Qb, unsigned short* __restrict__ Kb,
    unsigned short* __restrict__ Vtb)
{
    __shared__ unsigned short Xs[2][16][776];   // 16-row X tile bf16, pad 776

    const int tid  = threadIdx.x;
    const int wave = tid >> 6, lane = tid & 63;
    const int row  = lane & 15, quad = lane >> 4;
    const int m0   = blockIdx.x * 128;

    // W prologue: 24 B-frags resident in registers (96 VGPRs)
    short8 bfr[24];
    {
        const unsigned short* wp = Wt + (size_t)(wave * 16 + row) * E_DIM + quad * 8;
#pragma unroll
        for (int ks = 0; ks < 24; ++ks) bfr[ks] = *(const short8*)(wp + ks * 32);
    }

    const int srow = tid & 15;
    const int sc   = tid >> 4;
    const float* __restrict__ xbase = X + (size_t)(m0 + srow) * E_DIM + sc * 16;

    float4 fx[4];
#define LDX(mt)                                                               \
    {                                                                         \
        const float* p = xbase + (size_t)(mt) * 16 * E_DIM;                   \
        fx[0] = *(const float4*)(p);     fx[1] = *(const float4*)(p + 4);     \
        fx[2] = *(const float4*)(p + 8); fx[3] = *(const float4*)(p + 12);    \
    }
#define STX(buf)                                                              \
    {                                                                         \
        unsigned int tmp[8];                                                  \
        tmp[0] = pk2(fx[0].x, fx[0].y); tmp[1] = pk2(fx[0].z, fx[0].w);       \
        tmp[2] = pk2(fx[1].x, fx[1].y); tmp[3] = pk2(fx[1].z, fx[1].w);       \
        tmp[4] = pk2(fx[2].x, fx[2].y); tmp[5] = pk2(fx[2].z, fx[2].w);       \
        tmp[6] = pk2(fx[3].x, fx[3].y); tmp[7] = pk2(fx[3].z, fx[3].w);       \
        *(int4*)&Xs[buf][srow][sc * 16]     = *(int4*)&tmp[0];                \
        *(int4*)&Xs[buf][srow][sc * 16 + 8] = *(int4*)&tmp[4];                \
    }

    LDX(0); STX(0);
    RAWBAR();

    const int g  = wave >> 2;            // 0=Q, 1=K, 2=V
    const int h  = (wave & 3) * 16 + row;
    unsigned short* __restrict__ OQK = (g == 0) ? Qb : Kb;
    const int bb = m0 >> 12;

    int cur = 0;
    for (int mt = 0; mt < 8; ++mt) {
        if (mt < 7) LDX(mt + 1);

        floatx4 acc = (floatx4)0.0f;
#pragma unroll
        for (int ks = 0; ks < 24; ++ks) {
            const short8 af = *(const short8*)&Xs[cur][row][ks * 32 + quad * 8];
            acc = __builtin_amdgcn_mfma_f32_16x16x32_bf16(af, bfr[ks], acc, 0, 0, 0);
        }

        const int mr = m0 + mt * 16 + quad * 4;
        if (g < 2) {
#pragma unroll
            for (int r = 0; r < 4; ++r)
                OQK[(size_t)(mr + r) * H_DIM + h] = bf1(acc[r]);
        } else {
            const int t0 = mr & 4095;
            unsigned int u[2];
            u[0] = pk2(acc[0], acc[1]); u[1] = pk2(acc[2], acc[3]);
            *(uint2*)(Vtb + ((size_t)bb * H_DIM + h) * T_SZ + t0) = *(uint2*)u;
        }

        if (mt < 7) STX(cur ^ 1);
        RAWBAR();
        cur ^= 1;
    }
#undef LDX
#undef STX
}

// ---------------- flash attention: 32-row q-tiles, 4 waves = (q-half x key-half) ----------------
// K/V staged once per block into LDS (single buffer, 1-ahead register prefetch, raw barriers).
// No-max softmax => split-key partials additive; one LDS combine per block.
__global__ __launch_bounds__(256, 4) void attn_mfma(
    const unsigned short* __restrict__ Qb,
    const unsigned short* __restrict__ Kb,
    const unsigned short* __restrict__ Vtb,
    float* __restrict__ Out)
{
    // KV[0] = K tile [key][h], KV[1] = V^T tile [h][key]; aliased as Oc (float[4][16][64]) for combine
    __shared__ __align__(16) unsigned short KV[2][64][72];   // 18432 B
    __shared__ __align__(16) unsigned short Ps[4][16][40];   // per-wave P [q16][key32], 5120 B
    __shared__ float lc[4][16];

    const int lb   = blockIdx.x;
    const int b    = lb & 7;                   // batch -> XCD (L2 locality)
    const int qq   = 127 - (lb >> 3);          // 32-row q-tile, heavy first (LPT)
    const int tid  = threadIdx.x;
    const int wave = tid >> 6, lane = tid & 63;
    const int col  = lane & 15, quad = lane >> 4;
    const int wq   = wave >> 1;                // q-half (rows wq*16..)
    const int wk   = wave & 1;                 // key-half (keys wk*32..)

    const size_t base = (size_t)b * T_SZ * H_DIM;
    const int q0  = qq * 32;
    const int nkt = (qq >> 1) + 1;             // 64-key tiles needed
    const int ktd = nkt - 1;                   // diagonal tile

    // Q fragments for this wave's 16 q-rows
    short8 qf0, qf1;
    {
        const unsigned short* qp = Qb + base + (size_t)(q0 + wq * 16 + col) * H_DIM + quad * 8;
        qf0 = *(const short8*)(qp);
        qf1 = *(const short8*)(qp + 32);
    }

    floatx4 o[4];
#pragma unroll
    for (int i = 0; i < 4; ++i) o[i] = (floatx4)0.0f;
    float lp[4] = {0.0f, 0.0f, 0.0f, 0.0f};

    // cooperative staging: 32B of K + 32B of V^T per thread per tile
    const int krow = tid >> 2, kcol = (tid & 3) * 16;
    const unsigned short* __restrict__ Ksrc = Kb + base + (size_t)krow * H_DIM + kcol;
    const unsigned short* __restrict__ Vsrc = Vtb + ((size_t)b * H_DIM + krow) * T_SZ + kcol;

    int4 kr0, kr1, vr0, vr1;
#define LDKV(t)                                                          \
    {                                                                    \
        const unsigned short* kp = Ksrc + (size_t)(t) * 64 * H_DIM;      \
        kr0 = *(const int4*)kp; kr1 = *(const int4*)(kp + 8);            \
        const unsigned short* vp = Vsrc + (t) * 64;                      \
        vr0 = *(const int4*)vp; vr1 = *(const int4*)(vp + 8);            \
    }
#define STKV()                                                           \
    {                                                                    \
        *(int4*)&KV[0][krow][kcol] = kr0; *(int4*)&KV[0][krow][kcol + 8] = kr1; \
        *(int4*)&KV[1][krow][kcol] = vr0; *(int4*)&KV[1][krow][kcol + 8] = vr1; \
    }

    LDKV(0);
    STKV();
    RAWBAR();

    for (int kt = 0; kt < nkt; ++kt) {
        if (kt + 1 < nkt) LDKV(kt + 1);        // in flight across compute + barriers

        // S = Q K^T on this wave's 16q x 32k patch (2 key-ntiles)
        floatx4 s[2];
#pragma unroll
        for (int j = 0; j < 2; ++j) {
            const unsigned short* kp = &KV[0][(wk * 2 + j) * 16 + col][quad * 8];
            floatx4 a = (floatx4)0.0f;
            a = __builtin_amdgcn_mfma_f32_16x16x32_bf16(qf0, *(const short8*)(kp),      a, 0, 0, 0);
            a = __builtin_amdgcn_mfma_f32_16x16x32_bf16(qf1, *(const short8*)(kp + 32), a, 0, 0, 0);
            s[j] = a;
        }

        if (kt == ktd) {                       // causal mask on diagonal tile
#pragma unroll
            for (int j = 0; j < 2; ++j) {
                const int keyg = kt * 64 + wk * 32 + j * 16 + col;
#pragma unroll
                for (int r = 0; r < 4; ++r)
                    if (keyg > q0 + wq * 16 + quad * 4 + r) s[j][r] = -1e30f;
            }
        }

        // no-max softmax (Q pre-scaled by log2e): p = exp2(min(s,110))
#pragma unroll
        for (int r = 0; r < 4; ++r) {
#pragma unroll
            for (int j = 0; j < 2; ++j) {
                const float pv = exp2f(fminf(s[j][r], 110.0f));
                lp[r] += pv;
                Ps[wave][quad * 4 + r][j * 16 + col] = bf1(pv);
            }
        }
        __builtin_amdgcn_wave_barrier();       // per-wave LDS RAW ordering fence

        // O += P V over this wave's 32 keys (single K=32 MFMA per h-ntile)
        {
            const short8 pa = *(const short8*)(&Ps[wave][col][quad * 8]);
#pragma unroll
            for (int d = 0; d < 4; ++d) {
                const short8 vb = *(const short8*)(&KV[1][d * 16 + col][wk * 32 + quad * 8]);
                o[d] = __builtin_amdgcn_mfma_f32_16x16x32_bf16(pa, vb, o[d], 0, 0, 0);
            }
        }

        RAWBAR();                              // all waves done reading KV
        if (kt + 1 < nkt) STKV();
        RAWBAR();
    }

    // l partials: reduce over the 16 col-lanes of each quad group
#pragma unroll
    for (int r = 0; r < 4; ++r) {
        float l = lp[r];
#pragma unroll
        for (int off = 1; off < 16; off <<= 1)
            l += __shfl_xor(l, off, 16);
        if (col == 0) lc[wave][quad * 4 + r] = l;
    }
    __syncthreads();                           // all waves done with KV; lc visible

    // O partials into the KV area (Oc[wave][q16][64])
    float* __restrict__ Oc = (float*)&KV[0][0][0];
#pragma unroll
    for (int r = 0; r < 4; ++r)
#pragma unroll
        for (int d = 0; d < 4; ++d)
            Oc[((wave * 16) + quad * 4 + r) * 64 + d * 16 + col] = o[d][r];
    __syncthreads();

    // combine: rows 0-15 <- waves 0+1, rows 16-31 <- waves 2+3
    {
        const int orow = tid >> 3;             // 0..31
        const int d0   = (tid & 7) * 8;        // 0..56
        const int rl   = orow & 15;
        const int wb   = (orow >> 4) * 2;
        const float* p0 = &Oc[((wb * 16) + rl) * 64 + d0];
        const float* p1 = &Oc[(((wb + 1) * 16) + rl) * 64 + d0];
        const float inv = 1.0f / (lc[wb][rl] + lc[wb + 1][rl]);
        float4 a0 = *(const float4*)(p0);
        float4 a1 = *(const float4*)(p0 + 4);
        const float4 b0 = *(const float4*)(p1);
        const float4 b1 = *(const float4*)(p1 + 4);
        a0.x = (a0.x + b0.x) * inv; a0.y = (a0.y + b0.y) * inv;
        a0.z = (a0.z + b0.z) * inv; a0.w = (a0.w + b0.w) * inv;
        a1.x = (a1.x + b1.x) * inv; a1.y = (a1.y + b1.y) * inv;
        a1.z = (a1.z + b1.z) * inv; a1.w = (a1.w + b1.w) * inv;
        float* op = Out + base + (size_t)(q0 + orow) * H_DIM + d0;
        *(float4*)(op)     = a0;
        *(float4*)(op + 4) = a1;
    }
#undef LDKV
#undef STKV
}

extern "C" void kernel_launch(void* const* d_in, const int* in_sizes, int n_in,
                              void* d_out, int out_size, void* d_ws, size_t ws_size,
                              hipStream_t stream) {
    const float* X  = (const float*)d_in[0];
    const float* Wq = (const float*)d_in[1];
    const float* Wk = (const float*)d_in[2];
    const float* Wv = (const float*)d_in[3];

    unsigned short* Wt  = (unsigned short*)d_ws;            // 192*768 bf16
    unsigned short* Qb  = Wt + (size_t)192 * E_DIM;
    unsigned short* Kb  = Qb + (size_t)BT * H_DIM;
    unsigned short* Vtb = Kb + (size_t)BT * H_DIM;          // V transposed [b][h][t]

    prep_w<<<dim3(3, 12), 256, 0, stream>>>(Wq, Wk, Wv, Wt);
    proj_mfma<<<256, 768, 0, stream>>>(X, Wt, Qb, Kb, Vtb);
    attn_mfma<<<1024, 256, 0, stream>>>(Qb, Kb, Vtb, (float*)d_out);
}